// Round 4
// baseline (293.028 us; speedup 1.0000x reference)
//
#include <hip/hip_runtime.h>
#include <math.h>

constexpr int B_  = 128;
constexpr int A_  = 2048;
constexpr int C_  = 128;
constexpr int H_  = 512;
constexpr int S_  = 3;
constexpr int NR_ = 2;
constexpr int PR_ = C_ + 3 + S_;      // 134
constexpr int PW_ = 3 * C_ + 3 + S_;  // 390

typedef float vfloat4 __attribute__((ext_vector_type(4)));

__device__ __forceinline__ float sigmoidf_(float x) { return 1.0f / (1.0f + expf(-x)); }
__device__ __forceinline__ float softplusf_(float x) {
  return fmaxf(x, 0.0f) + log1pf(expf(-fabsf(x)));
}

__device__ __forceinline__ float waveReduceSum(float v) {
#pragma unroll
  for (int off = 32; off; off >>= 1) v += __shfl_xor(v, off, 64);
  return v;
}
__device__ __forceinline__ float waveReduceMax(float v) {
#pragma unroll
  for (int off = 32; off; off >>= 1) v = fmaxf(v, __shfl_xor(v, off, 64));
  return v;
}

// ---------------------------------------------------------------------------
// Kernel 1: projections. One wave per TWO adjacent output scalars (K=512 dot).
// (Round-1 version, known-good; rv zeroing removed — mega writes rv fully.)
// ---------------------------------------------------------------------------
__global__ __launch_bounds__(256) void proj_kernel(
    const float* __restrict__ h, const float* __restrict__ Wr,
    const float* __restrict__ br, const float* __restrict__ Ww,
    const float* __restrict__ bw, float* __restrict__ pr, float* __restrict__ pw) {
  constexpr int NPR = NR_ * B_ * PR_;   // 34304
  constexpr int NPW = B_ * PW_;         // 49920
  int wave = (blockIdx.x * blockDim.x + threadIdx.x) >> 6;
  int lane = threadIdx.x & 63;
  int out0 = wave * 2;
  const float* w0row;
  const float* w1row;
  const float* hrow;
  float bias0, bias1;
  float* outp;
  if (out0 < NPR) {
    int r = out0 / (B_ * PR_);
    int rem = out0 - r * (B_ * PR_);
    int b = rem / PR_;
    int p = rem - b * PR_;
    w0row = Wr + (size_t)(r * PR_ + p) * H_;
    w1row = w0row + H_;
    hrow = h + (size_t)b * H_;
    bias0 = br[r * PR_ + p];
    bias1 = br[r * PR_ + p + 1];
    outp = pr + out0;
  } else {
    int w2 = out0 - NPR;
    if (w2 >= NPW) return;
    int b = w2 / PW_;
    int p = w2 - b * PW_;
    w0row = Ww + (size_t)p * H_;
    w1row = w0row + H_;
    hrow = h + (size_t)b * H_;
    bias0 = bw[p];
    bias1 = bw[p + 1];
    outp = pw + w2;
  }
  const float4* h4 = (const float4*)hrow;
  const float4* wa4 = (const float4*)w0row;
  const float4* wb4 = (const float4*)w1row;
  float4 a0 = h4[(lane << 1)];
  float4 a1 = h4[(lane << 1) + 1];
  float4 b0 = wa4[(lane << 1)];
  float4 b1 = wa4[(lane << 1) + 1];
  float4 c0 = wb4[(lane << 1)];
  float4 c1 = wb4[(lane << 1) + 1];
  float acc0 = a0.x * b0.x;
  acc0 = fmaf(a0.y, b0.y, acc0);
  acc0 = fmaf(a0.z, b0.z, acc0);
  acc0 = fmaf(a0.w, b0.w, acc0);
  acc0 = fmaf(a1.x, b1.x, acc0);
  acc0 = fmaf(a1.y, b1.y, acc0);
  acc0 = fmaf(a1.z, b1.z, acc0);
  acc0 = fmaf(a1.w, b1.w, acc0);
  float acc1 = a0.x * c0.x;
  acc1 = fmaf(a0.y, c0.y, acc1);
  acc1 = fmaf(a0.z, c0.z, acc1);
  acc1 = fmaf(a0.w, c0.w, acc1);
  acc1 = fmaf(a1.x, c1.x, acc1);
  acc1 = fmaf(a1.y, c1.y, acc1);
  acc1 = fmaf(a1.z, c1.z, acc1);
  acc1 = fmaf(a1.w, c1.w, acc1);
  acc0 = waveReduceSum(acc0);
  acc1 = waveReduceSum(acc1);
  if (lane == 0) {
    outp[0] = acc0 + bias0;
    outp[1] = acc1 + bias1;
  }
}

// ---------------------------------------------------------------------------
// Kernel 2: mega-kernel. One block per batch b (grid=128, block=1024).
// Phase A: sim over all A rows (3 heads) -> LDS.
// Phase B: attention for 3 heads entirely in LDS (no global round-trip).
// Phase C: update pass (rv direct write + nmem NT store).
// All cross-phase deps are within one block: only __syncthreads needed.
// ---------------------------------------------------------------------------
__global__ __launch_bounds__(1024) void mega_kernel(
    const float* __restrict__ mem, const float* __restrict__ ra,
    const float* __restrict__ wa, const float* __restrict__ pr,
    const float* __restrict__ pw, float* __restrict__ rv,
    float* __restrict__ nmem) {
  __shared__ float sims[3][A_];              // 24 KB: sim, then attn in-place
  __shared__ float wg[A_];                   // 8 KB
  __shared__ __align__(16) float qs[3 * C_]; // 1.5 KB
  __shared__ float iqn[3];
  __shared__ float rbuf[16];
  __shared__ float4 red[2][16][32];          // 16 KB

  int b = blockIdx.x;
  int tid = threadIdx.x;
  int lane = tid & 63;
  int wv = tid >> 6;                         // 0..15

  // ---- q-prep: sigmoid + inverse norms
  if (tid < 3 * C_) {
    int hd = tid >> 7;
    int c = tid & (C_ - 1);
    float raw = (hd < 2) ? pr[(size_t)(hd * B_ + b) * PR_ + c]
                         : pw[(size_t)b * PW_ + c];
    qs[tid] = sigmoidf_(raw);
  }
  __syncthreads();
  if (wv < 3) {
    float v0 = qs[wv * C_ + lane];
    float v1 = qs[wv * C_ + 64 + lane];
    float ss = v0 * v0 + v1 * v1;
    ss = waveReduceSum(ss);
    if (lane == 0) iqn[wv] = 1.0f / fmaxf(sqrtf(ss), 1e-8f);
  }
  __syncthreads();

  // ---- Phase A: sim. 8 lanes per row; 128 rows per pass; 16 passes.
  {
    int j = tid & 7;
    int rgrp = tid >> 3;                     // 0..127
    float4 q0[4], q1[4], q2[4];
    const float4* qs4 = (const float4*)qs;
#pragma unroll
    for (int k = 0; k < 4; k++) {
      q0[k] = qs4[j + 8 * k];
      q1[k] = qs4[32 + j + 8 * k];
      q2[k] = qs4[64 + j + 8 * k];
    }
    float iq0 = iqn[0], iq1 = iqn[1], iq2 = iqn[2];
#pragma unroll 2
    for (int i = 0; i < 16; i++) {
      int row = (i << 7) + rgrp;
      const float4* mrow = (const float4*)(mem + ((size_t)b * A_ + row) * C_);
      float d0 = 0.f, d1 = 0.f, d2 = 0.f, ss = 0.f;
#pragma unroll
      for (int k = 0; k < 4; k++) {
        float4 m = mrow[j + 8 * k];
        d0 = fmaf(m.x, q0[k].x, d0); d0 = fmaf(m.y, q0[k].y, d0);
        d0 = fmaf(m.z, q0[k].z, d0); d0 = fmaf(m.w, q0[k].w, d0);
        d1 = fmaf(m.x, q1[k].x, d1); d1 = fmaf(m.y, q1[k].y, d1);
        d1 = fmaf(m.z, q1[k].z, d1); d1 = fmaf(m.w, q1[k].w, d1);
        d2 = fmaf(m.x, q2[k].x, d2); d2 = fmaf(m.y, q2[k].y, d2);
        d2 = fmaf(m.z, q2[k].z, d2); d2 = fmaf(m.w, q2[k].w, d2);
        ss = fmaf(m.x, m.x, ss); ss = fmaf(m.y, m.y, ss);
        ss = fmaf(m.z, m.z, ss); ss = fmaf(m.w, m.w, ss);
      }
#pragma unroll
      for (int off = 1; off <= 4; off <<= 1) {
        d0 += __shfl_xor(d0, off, 64);
        d1 += __shfl_xor(d1, off, 64);
        d2 += __shfl_xor(d2, off, 64);
        ss += __shfl_xor(ss, off, 64);
      }
      if (j == 0) {
        float imn = 1.0f / fmaxf(sqrtf(ss), 1e-8f);
        sims[0][row] = d0 * iq0 * imn;
        sims[1][row] = d1 * iq1 * imn;
        sims[2][row] = d2 * iq2 * imn;
      }
    }
  }
  __syncthreads();

  // ---- Phase B: attention per head, fully in LDS (2 elems/thread).
  for (int hd = 0; hd < 3; hd++) {
    const float* src = (hd < 2) ? (pr + (size_t)(hd * B_ + b) * PR_)
                                : (pw + (size_t)b * PW_);
    float braw = src[C_];
    float graw = src[C_ + 1];
    float s0r = src[C_ + 2], s1r = src[C_ + 3], s2r = src[C_ + 4];
    float gmraw = src[C_ + 5];
    float mx3 = fmaxf(s0r, fmaxf(s1r, s2r));
    float e0 = expf(s0r - mx3), e1 = expf(s1r - mx3), e2 = expf(s2r - mx3);
    float sinv = 1.0f / (e0 + e1 + e2);
    float beta = softplusf_(braw) + 1.0f;
    float gate = sigmoidf_(graw);
    float sw0 = e0 * sinv, sw1 = e1 * sinv, sw2 = e2 * sinv;
    float gamma = softplusf_(gmraw) + 1.0f;
    const float* prev = (hd < 2) ? (ra + (size_t)(hd * B_ + b) * A_)
                                 : (wa + (size_t)b * A_);

    float s0 = sims[hd][tid];
    float s1 = sims[hd][tid + 1024];
    float pv0 = prev[tid];
    float pv1 = prev[tid + 1024];

    float mx = fmaxf(s0, s1);
    mx = waveReduceMax(mx);
    if (lane == 0) rbuf[wv] = mx;
    __syncthreads();
    float M = rbuf[0];
#pragma unroll
    for (int i = 1; i < 16; i++) M = fmaxf(M, rbuf[i]);
    __syncthreads();

    float p0 = expf(beta * (s0 - M));
    float p1 = expf(beta * (s1 - M));
    float l = p0 + p1;
    l = waveReduceSum(l);
    if (lane == 0) rbuf[wv] = l;
    __syncthreads();
    float T = rbuf[0];
#pragma unroll
    for (int i = 1; i < 16; i++) T += rbuf[i];
    float inv = 1.0f / T;

    wg[tid] = fmaf(gate, p0 * inv, (1.0f - gate) * pv0);
    wg[tid + 1024] = fmaf(gate, p1 * inv, (1.0f - gate) * pv1);
    __syncthreads();

    float ws0 = sw0 * wg[(tid + 1) & (A_ - 1)] + sw1 * wg[tid] +
                sw2 * wg[(tid - 1) & (A_ - 1)];
    float ws1 = sw0 * wg[(tid + 1025) & (A_ - 1)] + sw1 * wg[tid + 1024] +
                sw2 * wg[(tid + 1023) & (A_ - 1)];
    float wp0 = (ws0 > 0.0f) ? exp2f(gamma * log2f(ws0)) : 0.0f;
    float wp1 = (ws1 > 0.0f) ? exp2f(gamma * log2f(ws1)) : 0.0f;
    float l2 = wp0 + wp1;
    l2 = waveReduceSum(l2);
    __syncthreads();                 // all rbuf reads (T) done before rewrite
    if (lane == 0) rbuf[wv] = l2;
    __syncthreads();
    float T2 = rbuf[0];
#pragma unroll
    for (int i = 1; i < 16; i++) T2 += rbuf[i];
    float inv2 = 1.0f / (T2 + 1e-12f);
    sims[hd][tid] = wp0 * inv2;
    sims[hd][tid + 1024] = wp1 * inv2;
    __syncthreads();                 // protect rbuf/wg for next head
  }

  // ---- Phase C: update. 32 lanes per row (quad c0), 64 rows per thread.
  {
    int quad = tid & 31;
    int rgrp = tid >> 5;                     // 0..31
    int c0 = quad << 2;
    const float* pwrow = pw + (size_t)b * PW_;
    float2 eA = *(const float2*)(pwrow + C_ + 6 + c0);
    float2 eB = *(const float2*)(pwrow + C_ + 6 + c0 + 2);
    float2 aA = *(const float2*)(pwrow + 2 * C_ + 6 + c0);
    float2 aB = *(const float2*)(pwrow + 2 * C_ + 6 + c0 + 2);
    float e0 = sigmoidf_(eA.x), e1 = sigmoidf_(eA.y), e2 = sigmoidf_(eB.x), e3 = sigmoidf_(eB.y);
    float ad0 = sigmoidf_(aA.x), ad1 = sigmoidf_(aA.y), ad2 = sigmoidf_(aB.x), ad3 = sigmoidf_(aB.y);

    float4 acc0 = make_float4(0.f, 0.f, 0.f, 0.f);
    float4 acc1 = make_float4(0.f, 0.f, 0.f, 0.f);

#pragma unroll 4
    for (int i = 0; i < 64; i++) {
      int row = (i << 5) + rgrp;
      size_t base = ((size_t)b * A_ + row) * C_ + c0;
      float4 m = *(const float4*)(mem + base);
      float w0 = sims[0][row];
      float w1 = sims[1][row];
      float ww = sims[2][row];
      acc0.x = fmaf(w0, m.x, acc0.x);
      acc0.y = fmaf(w0, m.y, acc0.y);
      acc0.z = fmaf(w0, m.z, acc0.z);
      acc0.w = fmaf(w0, m.w, acc0.w);
      acc1.x = fmaf(w1, m.x, acc1.x);
      acc1.y = fmaf(w1, m.y, acc1.y);
      acc1.z = fmaf(w1, m.z, acc1.z);
      acc1.w = fmaf(w1, m.w, acc1.w);
      vfloat4 nm;
      nm.x = fmaf(m.x, 1.0f - ww * e0, ww * ad0);
      nm.y = fmaf(m.y, 1.0f - ww * e1, ww * ad1);
      nm.z = fmaf(m.z, 1.0f - ww * e2, ww * ad2);
      nm.w = fmaf(m.w, 1.0f - ww * e3, ww * ad3);
      __builtin_nontemporal_store(nm, (vfloat4*)(nmem + base));
    }

    // fold rgrp pairs within each wave (lane 32 apart shares quad)
    acc0.x += __shfl_xor(acc0.x, 32, 64);
    acc0.y += __shfl_xor(acc0.y, 32, 64);
    acc0.z += __shfl_xor(acc0.z, 32, 64);
    acc0.w += __shfl_xor(acc0.w, 32, 64);
    acc1.x += __shfl_xor(acc1.x, 32, 64);
    acc1.y += __shfl_xor(acc1.y, 32, 64);
    acc1.z += __shfl_xor(acc1.z, 32, 64);
    acc1.w += __shfl_xor(acc1.w, 32, 64);
    if (lane < 32) {
      red[0][wv][lane] = acc0;
      red[1][wv][lane] = acc1;
    }
    __syncthreads();
    if (tid < 64) {
      int hd = tid >> 5;
      int q = tid & 31;
      float4 r = red[hd][0][q];
#pragma unroll
      for (int g = 1; g < 16; g++) {
        float4 t = red[hd][g][q];
        r.x += t.x; r.y += t.y; r.z += t.z; r.w += t.w;
      }
      float* rvp = rv + (size_t)(hd * B_ + b) * C_ + (q << 2);
      rvp[0] = r.x;
      rvp[1] = r.y;
      rvp[2] = r.z;
      rvp[3] = r.w;
    }
  }
}

extern "C" void kernel_launch(void* const* d_in, const int* in_sizes, int n_in,
                              void* d_out, int out_size, void* d_ws, size_t ws_size,
                              hipStream_t stream) {
  const float* h   = (const float*)d_in[0];
  const float* mem = (const float*)d_in[1];
  const float* ra  = (const float*)d_in[2];
  const float* wa  = (const float*)d_in[3];
  const float* Wr  = (const float*)d_in[4];
  const float* br  = (const float*)d_in[5];
  const float* Ww  = (const float*)d_in[6];
  const float* bw  = (const float*)d_in[7];

  float* out = (float*)d_out;
  float* rv = out;                               // [NR][B][C]
  float* nmem = out + NR_ * B_ * C_;             // [B][A][C]

  float* ws = (float*)d_ws;
  float* pr_buf = ws;                            // NR*B*PR = 34304
  float* pw_buf = pr_buf + NR_ * B_ * PR_;       // B*PW    = 49920

  constexpr int NPAIRS = (NR_ * B_ * PR_ + B_ * PW_) / 2;  // 42112 waves
  proj_kernel<<<dim3(NPAIRS / 4), dim3(256), 0, stream>>>(h, Wr, br, Ww, bw, pr_buf, pw_buf);
  mega_kernel<<<dim3(B_), dim3(1024), 0, stream>>>(mem, ra, wa, pr_buf, pw_buf, rv, nmem);
}